// Round 7
// baseline (236.965 us; speedup 1.0000x reference)
//
#include <hip/hip_runtime.h>

// Fused MHA: x(4,1024,1024) fp32, mask(4,1024) i32, w_qkv(3072,1024), b_qkv,
// w_out(1024,1024), b_out -> out(4,1024,1024) fp32.
// Pipeline: prep-cast -> mask-sum -> qkv GEMM (bf16 MFMA) -> flash attn -> out GEMM.
// R7: attn = 2 independent q-chains per wave (ILP x2, shared K/V loads) +
//     KV-split x4 + reg prefetch + exp2 defer-max softmax + tree merge.

#define NHEADS 16
#define DHEAD  64
#define EDIM   1024
#define SLEN   1024
#define BATCH  4

typedef short bf16x8 __attribute__((ext_vector_type(8)));
typedef float f32x4  __attribute__((ext_vector_type(4)));
typedef float f32x16 __attribute__((ext_vector_type(16)));

#define MFMA_BF16(a,b,c) __builtin_amdgcn_mfma_f32_16x16x32_bf16((a),(b),(c),0,0,0)
#define MFMA32(a,b,c)    __builtin_amdgcn_mfma_f32_32x32x16_bf16((a),(b),(c),0,0,0)

typedef const __attribute__((address_space(1))) void gvoid_t;
typedef __attribute__((address_space(3))) void lvoid_t;

__device__ __forceinline__ unsigned short f2bf(float x) {
  union { float f; unsigned int u; } v; v.f = x;
  unsigned int r = v.u + 0x7fffu + ((v.u >> 16) & 1u);
  return (unsigned short)(r >> 16);
}

__device__ __forceinline__ unsigned pack2(float lo, float hi) {
  return (unsigned)f2bf(lo) | ((unsigned)f2bf(hi) << 16);
}

__device__ __forceinline__ void gl2lds16(const void* g, void* l) {
  __builtin_amdgcn_global_load_lds((gvoid_t*)g, (lvoid_t*)l, 16, 0, 0);
}

// ---------------- prep: fp32 -> bf16 casts ----------------
__global__ __launch_bounds__(256) void prep_cast(
    const float* __restrict__ x, const float* __restrict__ wq,
    const float* __restrict__ wo,
    unsigned short* __restrict__ xb, unsigned short* __restrict__ wqb,
    unsigned short* __restrict__ wob) {
  int i = blockIdx.x * 256 + threadIdx.x;
  const int NX  = BATCH * SLEN * EDIM / 4;   // 1048576
  const int NW1 = 3 * EDIM * EDIM / 4;       // 786432
  const float4* src; unsigned short* dst; int j;
  if (i < NX)           { src = (const float4*)x;  dst = xb;  j = i; }
  else if (i < NX+NW1)  { src = (const float4*)wq; dst = wqb; j = i - NX; }
  else                  { src = (const float4*)wo; dst = wob; j = i - NX - NW1; }
  float4 v = src[j];
  ushort4 o;
  o.x = f2bf(v.x); o.y = f2bf(v.y); o.z = f2bf(v.z); o.w = f2bf(v.w);
  ((ushort4*)dst)[j] = o;
}

// ---------------- mask row-sum: L[b] ----------------
__global__ __launch_bounds__(256) void mask_sum(const int* __restrict__ mask,
                                                int* __restrict__ L) {
  int b = blockIdx.x;
  int t = threadIdx.x;
  int s = 0;
  for (int i = t; i < SLEN; i += 256) s += mask[b * SLEN + i];
  #pragma unroll
  for (int m = 1; m < 64; m <<= 1) s += __shfl_xor(s, m);
  __shared__ int part[4];
  if ((t & 63) == 0) part[t >> 6] = s;
  __syncthreads();
  if (t == 0) L[b] = part[0] + part[1] + part[2] + part[3];
}

// ---------------- GEMM C = A @ B^T (A:[M][K], B:[N][K], bf16, m97 structure) ----
template<int EPI>
__global__ __launch_bounds__(256) void gemm_bt(
    const unsigned short* __restrict__ A, const unsigned short* __restrict__ B,
    int M, int N, int K,
    const float* __restrict__ bias,
    float* __restrict__ outf,
    unsigned short* __restrict__ qb, unsigned short* __restrict__ kb,
    unsigned short* __restrict__ vb) {
  __shared__ __align__(16) unsigned short lds_a[128 * 32];
  __shared__ __align__(16) unsigned short lds_b[128 * 32];
  const int tid = threadIdx.x;
  const int w = tid >> 6, l = tid & 63;
  const int g = l >> 4, ln = l & 15;
  const int ntile = N >> 7;
  const int tm = blockIdx.x / ntile, tn = blockIdx.x % ntile;
  const int mBase = tm << 7, nBase = tn << 7;
  const int wr = w >> 1, wc = w & 1;

  f32x4 zz = {0.f, 0.f, 0.f, 0.f};
  f32x4 acc[4][4];
  #pragma unroll
  for (int m = 0; m < 4; ++m)
    #pragma unroll
    for (int n = 0; n < 4; ++n) acc[m][n] = zz;

  const int u0 = tid, u1 = tid + 256;
  const int r0 = u0 >> 2, c0 = (u0 & 3) << 3;
  const int r1 = u1 >> 2, c1 = (u1 & 3) << 3;
  const unsigned short* Ab = A + mBase * K;
  const unsigned short* Bb = B + nBase * K;
  unsigned short* da0 = &lds_a[(w * 64) * 8];
  unsigned short* da1 = &lds_a[(256 + w * 64) * 8];
  unsigned short* db0 = &lds_b[(w * 64) * 8];
  unsigned short* db1 = &lds_b[(256 + w * 64) * 8];

  for (int k0 = 0; k0 < K; k0 += 32) {
    gl2lds16(Ab + r0 * K + k0 + c0, da0);
    gl2lds16(Ab + r1 * K + k0 + c1, da1);
    gl2lds16(Bb + r0 * K + k0 + c0, db0);
    gl2lds16(Bb + r1 * K + k0 + c1, db1);
    __syncthreads();
    bf16x8 af[4], bfr[4];
    #pragma unroll
    for (int m = 0; m < 4; ++m)
      af[m] = *(const bf16x8*)&lds_a[(wr * 64 + m * 16 + ln) * 32 + g * 8];
    #pragma unroll
    for (int n = 0; n < 4; ++n)
      bfr[n] = *(const bf16x8*)&lds_b[(wc * 64 + n * 16 + ln) * 32 + g * 8];
    #pragma unroll
    for (int m = 0; m < 4; ++m)
      #pragma unroll
      for (int n = 0; n < 4; ++n)
        acc[m][n] = MFMA_BF16(af[m], bfr[n], acc[m][n]);
    __syncthreads();
  }

  #pragma unroll
  for (int m = 0; m < 4; ++m) {
    const int rowb = mBase + wr * 64 + m * 16 + g * 4;
    #pragma unroll
    for (int n = 0; n < 4; ++n) {
      const int col = nBase + wc * 64 + n * 16 + ln;
      const float bv = bias[col];
      #pragma unroll
      for (int r = 0; r < 4; ++r) {
        const float vv = acc[m][n][r] + bv;
        const int row = rowb + r;
        if (EPI == 0) {
          const int part = col >> 10;          // 0=q,1=k,2=v
          const int c = col & 1023;
          const int hh = c >> 6, d = c & 63;
          const int bb = row >> 10, s = row & 1023;
          const int bh = bb * NHEADS + hh;
          const unsigned short hv = f2bf(vv);
          if (part == 0)      qb[(bh * SLEN + s) * DHEAD + d] = hv;
          else if (part == 1) kb[(bh * SLEN + s) * DHEAD + d] = hv;
          else                vb[(bh * DHEAD + d) * SLEN + s] = hv;  // V^T
        } else {
          outf[row * N + col] = vv;
        }
      }
    }
  }
}

// ---------------- flash attention: 2 q-chains/wave + KV-split x4 -------------
// 256-thr blocks = 4 waves; block owns 64 q rows (chains A,B of 32); wave w
// does key-tiles t == w (mod 4). S^T = mfma(K,Q): lane q=lane&31, key
// crow(r,hi)=(r&3)+8*(r>>2)+4*hi. O^T = mfma(V^T,P): d=crow(r,hi) (+32 o1).
__global__ __launch_bounds__(256) void attn(
    const unsigned short* __restrict__ qb, const unsigned short* __restrict__ kb,
    const unsigned short* __restrict__ vb, const int* __restrict__ Lp,
    unsigned short* __restrict__ yb) {
  const int bid = blockIdx.x;
  const int lid = (bid & 7) * 128 + (bid >> 3);   // XCD-chunked swizzle (1024%8==0)
  const int bh = lid >> 4, qp = lid & 15;
  const int b = bh >> 4, h = bh & 15;
  const int L = Lp[b];
  const int tid = threadIdx.x;
  const int w = tid >> 6, l = tid & 63;
  const int l31 = l & 31, hi = l >> 5;
  const int q0 = qp * 64;
  const int qA = q0 + l31, qB = q0 + 32 + l31;
  const int qwA = 2 * qp, qwB = 2 * qp + 1;

  const unsigned short* qp_ = qb + (size_t)bh * SLEN * DHEAD;
  const unsigned short* kp  = kb + (size_t)bh * SLEN * DHEAD;
  const unsigned short* vp  = vb + (size_t)bh * DHEAD * SLEN;

  bf16x8 qfA[4], qfB[4];
  #pragma unroll
  for (int c = 0; c < 4; ++c) {
    qfA[c] = *(const bf16x8*)&qp_[qA * DHEAD + c * 16 + hi * 8];
    qfB[c] = *(const bf16x8*)&qp_[qB * DHEAD + c * 16 + hi * 8];
  }

  f32x16 o0A = {}, o1A = {}, o0B = {}, o1B = {};
  float mA = -__builtin_inff(), lsA = 0.f;
  float mB = -__builtin_inff(), lsB = 0.f;
  const float C = 0.18033688011112042f;          // 0.125 * log2(e)

  const bool noneA = q0 >= L,        noneB = (q0 + 32) >= L;
  const bool allA  = (q0 + 31) < L,  allB  = (q0 + 63) < L;
  const int tsA = (allA && L < SLEN) ? qwA : 0;
  const int tsB = (allB && L < SLEN) ? qwB : 0;
  const int ts  = tsA < tsB ? tsA : tsB;
  const int tlo = ts + ((w - ts) & 3);

  const int tp = tlo < 32 ? tlo : 31;
  bf16x8 kcur[4];
  #pragma unroll
  for (int c = 0; c < 4; ++c)
    kcur[c] = *(const bf16x8*)&kp[(tp * 32 + l31) * DHEAD + c * 16 + hi * 8];

#define SM_PV(SUF)                                                          \
  {                                                                         \
    const bool domask = (!none##SUF) && (t <= qw##SUF);                     \
    float pm = -__builtin_inff();                                           \
    if (domask) {                                                           \
      _Pragma("unroll")                                                     \
      for (int r = 0; r < 16; ++r) {                                        \
        const int key = kb0 + (r & 3) + 8 * (r >> 2) + 4 * hi;              \
        float s = e##SUF[r] * C;                                            \
        if ((q##SUF < L) && (key <= q##SUF)) s = -1e30f;                    \
        e##SUF[r] = s; pm = fmaxf(pm, s);                                   \
      }                                                                     \
    } else {                                                                \
      _Pragma("unroll")                                                     \
      for (int r = 0; r < 16; ++r) {                                        \
        const float s = e##SUF[r] * C; e##SUF[r] = s; pm = fmaxf(pm, s);    \
      }                                                                     \
    }                                                                       \
    pm = fmaxf(pm, __shfl_xor(pm, 32));                                     \
    const bool need = !__all(pm <= m##SUF + 8.0f);                          \
    if (need) {                                                             \
      const float mn = fmaxf(m##SUF, pm);                                   \
      const float a = exp2f(m##SUF - mn);                                   \
      _Pragma("unroll")                                                     \
      for (int r = 0; r < 16; ++r) { o0##SUF[r] *= a; o1##SUF[r] *= a; }    \
      ls##SUF *= a; m##SUF = mn;                                            \
    }                                                                       \
    float sum = 0.f;                                                        \
    _Pragma("unroll")                                                       \
    for (int r = 0; r < 16; ++r) {                                          \
      const float pe = exp2f(e##SUF[r] - m##SUF);                           \
      e##SUF[r] = pe; sum += pe;                                            \
    }                                                                       \
    sum += __shfl_xor(sum, 32);                                             \
    ls##SUF += sum;                                                         \
    bf16x8 pbf[2];                                                          \
    _Pragma("unroll")                                                       \
    for (int kc = 0; kc < 2; ++kc) {                                        \
      const unsigned wA_ = pack2(e##SUF[8*kc+0], e##SUF[8*kc+1]);           \
      const unsigned wB_ = pack2(e##SUF[8*kc+2], e##SUF[8*kc+3]);           \
      const unsigned wC_ = pack2(e##SUF[8*kc+4], e##SUF[8*kc+5]);           \
      const unsigned wD_ = pack2(e##SUF[8*kc+6], e##SUF[8*kc+7]);           \
      const unsigned pA_ = __shfl_xor(wA_, 32);                             \
      const unsigned pB_ = __shfl_xor(wB_, 32);                             \
      const unsigned pC_ = __shfl_xor(wC_, 32);                             \
      const unsigned pD_ = __shfl_xor(wD_, 32);                             \
      union { unsigned u[4]; bf16x8 v; } pk;                                \
      pk.u[0] = hi ? pC_ : wA_;                                             \
      pk.u[1] = hi ? pD_ : wB_;                                             \
      pk.u[2] = hi ? wC_ : pA_;                                             \
      pk.u[3] = hi ? wD_ : pB_;                                             \
      pbf[kc] = pk.v;                                                       \
    }                                                                       \
    __builtin_amdgcn_s_setprio(1);                                          \
    o0##SUF = MFMA32(vf0[0], pbf[0], o0##SUF);                              \
    o1##SUF = MFMA32(vf1[0], pbf[0], o1##SUF);                              \
    o0##SUF = MFMA32(vf0[1], pbf[1], o0##SUF);                              \
    o1##SUF = MFMA32(vf1[1], pbf[1], o1##SUF);                              \
    __builtin_amdgcn_s_setprio(0);                                          \
  }

  for (int t = tlo; t < 32; t += 4) {
    const int kb0 = t * 32;
    const int tn = (t + 4 < 32) ? (t + 4) : t;
    bf16x8 knxt[4];
    #pragma unroll
    for (int c = 0; c < 4; ++c)
      knxt[c] = *(const bf16x8*)&kp[(tn * 32 + l31) * DHEAD + c * 16 + hi * 8];
    bf16x8 vf0[2], vf1[2];
    #pragma unroll
    for (int kc = 0; kc < 2; ++kc) {
      vf0[kc] = *(const bf16x8*)&vp[l31 * SLEN + kb0 + kc * 16 + hi * 8];
      vf1[kc] = *(const bf16x8*)&vp[(32 + l31) * SLEN + kb0 + kc * 16 + hi * 8];
    }

    f32x16 eA = {}, eB = {};
    __builtin_amdgcn_s_setprio(1);
    #pragma unroll
    for (int c = 0; c < 4; ++c) eA = MFMA32(kcur[c], qfA[c], eA);
    #pragma unroll
    for (int c = 0; c < 4; ++c) eB = MFMA32(kcur[c], qfB[c], eB);
    __builtin_amdgcn_s_setprio(0);

    if (t >= tsA) SM_PV(A)
    if (t >= tsB) SM_PV(B)

    #pragma unroll
    for (int c = 0; c < 4; ++c) kcur[c] = knxt[c];
  }
#undef SM_PV

  // ---------------- 4-wave pairwise-tree merge (both chains) ----------------
  __shared__ float mlsA[4][2][32], mlsB[4][2][32];
  __shared__ __align__(16) float obufA[2][32][65], obufB[2][32][65];
  if (hi == 0) {
    mlsA[w][0][l31] = mA; mlsA[w][1][l31] = lsA;
    mlsB[w][0][l31] = mB; mlsB[w][1][l31] = lsB;
  }
  __syncthreads();
  {
    const float a0 = mlsA[0][0][l31], a1 = mlsA[1][0][l31];
    const float a2 = mlsA[2][0][l31], a3 = mlsA[3][0][l31];
    const float msA = fmaxf(fmaxf(a0, a1), fmaxf(a2, a3));
    const float dnA = mlsA[0][1][l31] * exp2f(a0 - msA)
                    + mlsA[1][1][l31] * exp2f(a1 - msA)
                    + mlsA[2][1][l31] * exp2f(a2 - msA)
                    + mlsA[3][1][l31] * exp2f(a3 - msA);
    const float swA = exp2f(mA - msA) / dnA;
    #pragma unroll
    for (int r = 0; r < 16; ++r) { o0A[r] *= swA; o1A[r] *= swA; }
    const float b0 = mlsB[0][0][l31], b1 = mlsB[1][0][l31];
    const float b2 = mlsB[2][0][l31], b3 = mlsB[3][0][l31];
    const float msB = fmaxf(fmaxf(b0, b1), fmaxf(b2, b3));
    const float dnB = mlsB[0][1][l31] * exp2f(b0 - msB)
                    + mlsB[1][1][l31] * exp2f(b1 - msB)
                    + mlsB[2][1][l31] * exp2f(b2 - msB)
                    + mlsB[3][1][l31] * exp2f(b3 - msB);
    const float swB = exp2f(mB - msB) / dnB;
    #pragma unroll
    for (int r = 0; r < 16; ++r) { o0B[r] *= swB; o1B[r] *= swB; }
  }
  if (w >= 2) {
    #pragma unroll
    for (int r = 0; r < 16; ++r) {
      const int d = (r & 3) + 8 * (r >> 2) + 4 * hi;
      obufA[w - 2][l31][d]      = o0A[r];
      obufA[w - 2][l31][d + 32] = o1A[r];
      obufB[w - 2][l31][d]      = o0B[r];
      obufB[w - 2][l31][d + 32] = o1B[r];
    }
  }
  __syncthreads();
  if (w < 2) {
    #pragma unroll
    for (int r = 0; r < 16; ++r) {
      const int d = (r & 3) + 8 * (r >> 2) + 4 * hi;
      o0A[r] += obufA[w][l31][d];
      o1A[r] += obufA[w][l31][d + 32];
      o0B[r] += obufB[w][l31][d];
      o1B[r] += obufB[w][l31][d + 32];
    }
  }
  __syncthreads();
  if (w == 1) {
    #pragma unroll
    for (int r = 0; r < 16; ++r) {
      const int d = (r & 3) + 8 * (r >> 2) + 4 * hi;
      obufA[0][l31][d]      = o0A[r];
      obufA[0][l31][d + 32] = o1A[r];
      obufB[0][l31][d]      = o0B[r];
      obufB[0][l31][d + 32] = o1B[r];
    }
  }
  __syncthreads();
  if (w == 0) {
    #pragma unroll
    for (int r = 0; r < 16; ++r) {
      const int d = (r & 3) + 8 * (r >> 2) + 4 * hi;
      o0A[r] += obufA[0][l31][d];
      o1A[r] += obufA[0][l31][d + 32];
      o0B[r] += obufB[0][l31][d];
      o1B[r] += obufB[0][l31][d + 32];
    }
    unsigned short* yrA = yb + (size_t)(b * SLEN + qA) * EDIM + h * DHEAD;
    unsigned short* yrB = yb + (size_t)(b * SLEN + qB) * EDIM + h * DHEAD;
    #pragma unroll
    for (int rq = 0; rq < 4; ++rq) {
      ushort4 s0, s1;
      s0.x = f2bf(o0A[4*rq+0]); s0.y = f2bf(o0A[4*rq+1]);
      s0.z = f2bf(o0A[4*rq+2]); s0.w = f2bf(o0A[4*rq+3]);
      s1.x = f2bf(o1A[4*rq+0]); s1.y = f2bf(o1A[4*rq+1]);
      s1.z = f2bf(o1A[4*rq+2]); s1.w = f2bf(o1A[4*rq+3]);
      *(ushort4*)&yrA[8*rq + 4*hi]      = s0;
      *(ushort4*)&yrA[32 + 8*rq + 4*hi] = s1;
      s0.x = f2bf(o0B[4*rq+0]); s0.y = f2bf(o0B[4*rq+1]);
      s0.z = f2bf(o0B[4*rq+2]); s0.w = f2bf(o0B[4*rq+3]);
      s1.x = f2bf(o1B[4*rq+0]); s1.y = f2bf(o1B[4*rq+1]);
      s1.z = f2bf(o1B[4*rq+2]); s1.w = f2bf(o1B[4*rq+3]);
      *(ushort4*)&yrB[8*rq + 4*hi]      = s0;
      *(ushort4*)&yrB[32 + 8*rq + 4*hi] = s1;
    }
  }
}

// ---------------- launch ----------------
extern "C" void kernel_launch(void* const* d_in, const int* in_sizes, int n_in,
                              void* d_out, int out_size, void* d_ws, size_t ws_size,
                              hipStream_t stream) {
  const float* x    = (const float*)d_in[0];
  const int*   mask = (const int*)d_in[1];
  const float* wqkv = (const float*)d_in[2];
  const float* bqkv = (const float*)d_in[3];
  const float* wout = (const float*)d_in[4];
  const float* bout = (const float*)d_in[5];
  float* out = (float*)d_out;

  char* ws = (char*)d_ws;
  const size_t SZ_X   = (size_t)BATCH * SLEN * EDIM * 2;   // 8MB
  const size_t SZ_WQ  = (size_t)3 * EDIM * EDIM * 2;       // 6MB
  const size_t SZ_WO  = (size_t)EDIM * EDIM * 2;           // 2MB
  const size_t SZ_QKV = (size_t)BATCH * NHEADS * SLEN * DHEAD * 2;  // 8MB each

  unsigned short* xb   = (unsigned short*)ws;               ws += SZ_X;
  unsigned short* wqb  = (unsigned short*)ws;               ws += SZ_WQ;
  unsigned short* wob  = (unsigned short*)ws;               ws += SZ_WO;
  unsigned short* qbuf = (unsigned short*)ws;               ws += SZ_QKV;
  unsigned short* kbuf = (unsigned short*)ws;               ws += SZ_QKV;
  unsigned short* vbuf = (unsigned short*)ws;               ws += SZ_QKV;
  unsigned short* ybuf = (unsigned short*)ws;               ws += SZ_X;
  int* Lbuf = (int*)ws;

  prep_cast<<<8192, 256, 0, stream>>>(x, wqkv, wout, xb, wqb, wob);
  mask_sum<<<BATCH, 256, 0, stream>>>(mask, Lbuf);
  gemm_bt<0><<<(4096 / 128) * (3072 / 128), 256, 0, stream>>>(
      xb, wqb, 4096, 3072, 1024, bqkv, nullptr, qbuf, kbuf, vbuf);
  attn<<<BATCH * NHEADS * (SLEN / 64), 256, 0, stream>>>(qbuf, kbuf, vbuf, Lbuf, ybuf);
  gemm_bt<1><<<(4096 / 128) * (1024 / 128), 256, 0, stream>>>(
      ybuf, wob, 4096, 1024, 1024, bout, out, nullptr, nullptr, nullptr);
}

// Round 9
// 222.844 us; speedup vs baseline: 1.0634x; 1.0634x over previous
//
#include <hip/hip_runtime.h>

// Fused MHA: x(4,1024,1024) fp32, mask(4,1024) i32, w_qkv(3072,1024), b_qkv,
// w_out(1024,1024), b_out -> out(4,1024,1024) fp32.
// R9: isolation round. attn exchange = PROVEN shfl_xor/f2bf primitives (R3),
//     keep R8's fused A/B softmax block + tree-max. GEMMs keep R8's 2-phase
//     double-buffer + XCD swizzle + vectorized V^T epilogue.

#define NHEADS 16
#define DHEAD  64
#define EDIM   1024
#define SLEN   1024
#define BATCH  4

typedef short bf16x8 __attribute__((ext_vector_type(8)));
typedef float f32x4  __attribute__((ext_vector_type(4)));
typedef float f32x16 __attribute__((ext_vector_type(16)));

#define MFMA_BF16(a,b,c) __builtin_amdgcn_mfma_f32_16x16x32_bf16((a),(b),(c),0,0,0)
#define MFMA32(a,b,c)    __builtin_amdgcn_mfma_f32_32x32x16_bf16((a),(b),(c),0,0,0)

typedef const __attribute__((address_space(1))) void gvoid_t;
typedef __attribute__((address_space(3))) void lvoid_t;

__device__ __forceinline__ unsigned short f2bf(float x) {
  union { float f; unsigned int u; } v; v.f = x;
  unsigned int r = v.u + 0x7fffu + ((v.u >> 16) & 1u);
  return (unsigned short)(r >> 16);
}

__device__ __forceinline__ unsigned pack2(float lo, float hi) {
  return (unsigned)f2bf(lo) | ((unsigned)f2bf(hi) << 16);
}

__device__ __forceinline__ void gl2lds16(const void* g, void* l) {
  __builtin_amdgcn_global_load_lds((gvoid_t*)g, (lvoid_t*)l, 16, 0, 0);
}

// ---------------- prep: fp32 -> bf16 casts ----------------
__global__ __launch_bounds__(256) void prep_cast(
    const float* __restrict__ x, const float* __restrict__ wq,
    const float* __restrict__ wo,
    unsigned short* __restrict__ xb, unsigned short* __restrict__ wqb,
    unsigned short* __restrict__ wob) {
  int i = blockIdx.x * 256 + threadIdx.x;
  const int NX  = BATCH * SLEN * EDIM / 4;   // 1048576
  const int NW1 = 3 * EDIM * EDIM / 4;       // 786432
  const float4* src; unsigned short* dst; int j;
  if (i < NX)           { src = (const float4*)x;  dst = xb;  j = i; }
  else if (i < NX+NW1)  { src = (const float4*)wq; dst = wqb; j = i - NX; }
  else                  { src = (const float4*)wo; dst = wob; j = i - NX - NW1; }
  float4 v = src[j];
  ushort4 o;
  o.x = f2bf(v.x); o.y = f2bf(v.y); o.z = f2bf(v.z); o.w = f2bf(v.w);
  ((ushort4*)dst)[j] = o;
}

// ---------------- mask row-sum: L[b] ----------------
__global__ __launch_bounds__(256) void mask_sum(const int* __restrict__ mask,
                                                int* __restrict__ L) {
  int b = blockIdx.x;
  int t = threadIdx.x;
  int s = 0;
  for (int i = t; i < SLEN; i += 256) s += mask[b * SLEN + i];
  #pragma unroll
  for (int m = 1; m < 64; m <<= 1) s += __shfl_xor(s, m);
  __shared__ int part[4];
  if ((t & 63) == 0) part[t >> 6] = s;
  __syncthreads();
  if (t == 0) L[b] = part[0] + part[1] + part[2] + part[3];
}

// ---------------- GEMM C = A @ B^T, 2-phase double-buffered ----------------
template<int EPI>
__global__ __launch_bounds__(256) void gemm_bt(
    const unsigned short* __restrict__ A, const unsigned short* __restrict__ B,
    int M, int N, int K,
    const float* __restrict__ bias,
    float* __restrict__ outf,
    unsigned short* __restrict__ qb, unsigned short* __restrict__ kb,
    unsigned short* __restrict__ vb) {
  __shared__ __align__(16) unsigned short lds_a[2][128 * 32];
  __shared__ __align__(16) unsigned short lds_b[2][128 * 32];
  const int tid = threadIdx.x;
  const int w = tid >> 6, l = tid & 63;
  const int g = l >> 4, ln = l & 15;
  const int ntile = N >> 7;
  // XCD-chunked swizzle (grid % 8 == 0 for both instantiations)
  const int nwg = gridDim.x;
  const int bid = blockIdx.x;
  const int wg = (bid & 7) * (nwg >> 3) + (bid >> 3);
  const int tm = wg / ntile, tn = wg % ntile;
  const int mBase = tm << 7, nBase = tn << 7;
  const int wr = w >> 1, wc = w & 1;

  f32x4 zz = {0.f, 0.f, 0.f, 0.f};
  f32x4 acc[4][4];
  #pragma unroll
  for (int m = 0; m < 4; ++m)
    #pragma unroll
    for (int n = 0; n < 4; ++n) acc[m][n] = zz;

  const int u0 = tid, u1 = tid + 256;
  const int r0 = u0 >> 2, c0 = (u0 & 3) << 3;
  const int r1 = u1 >> 2, c1 = (u1 & 3) << 3;
  const unsigned short* Ab = A + mBase * K;
  const unsigned short* Bb = B + nBase * K;
  const int d0 = (w * 64) * 8, d1 = (256 + w * 64) * 8;

  const int NT = K >> 5;
  // prologue: stage tile 0 into buf 0
  gl2lds16(Ab + r0 * K + c0, &lds_a[0][d0]);
  gl2lds16(Ab + r1 * K + c1, &lds_a[0][d1]);
  gl2lds16(Bb + r0 * K + c0, &lds_b[0][d0]);
  gl2lds16(Bb + r1 * K + c1, &lds_b[0][d1]);
  __syncthreads();

  int cur = 0;
  for (int t = 0; t < NT; ++t) {
    if (t + 1 < NT) {   // stage next tile first (latency hides under MFMA)
      const int kn = (t + 1) << 5;
      gl2lds16(Ab + r0 * K + kn + c0, &lds_a[cur ^ 1][d0]);
      gl2lds16(Ab + r1 * K + kn + c1, &lds_a[cur ^ 1][d1]);
      gl2lds16(Bb + r0 * K + kn + c0, &lds_b[cur ^ 1][d0]);
      gl2lds16(Bb + r1 * K + kn + c1, &lds_b[cur ^ 1][d1]);
    }
    bf16x8 af[4], bfr[4];
    #pragma unroll
    for (int m = 0; m < 4; ++m)
      af[m] = *(const bf16x8*)&lds_a[cur][(wr * 64 + m * 16 + ln) * 32 + g * 8];
    #pragma unroll
    for (int n = 0; n < 4; ++n)
      bfr[n] = *(const bf16x8*)&lds_b[cur][(wc * 64 + n * 16 + ln) * 32 + g * 8];
    __builtin_amdgcn_s_setprio(1);
    #pragma unroll
    for (int m = 0; m < 4; ++m)
      #pragma unroll
      for (int n = 0; n < 4; ++n)
        acc[m][n] = MFMA_BF16(af[m], bfr[n], acc[m][n]);
    __builtin_amdgcn_s_setprio(0);
    __syncthreads();   // drains vmcnt(0)+lgkmcnt(0): next buffer staged & ready
    cur ^= 1;
  }

  #pragma unroll
  for (int m = 0; m < 4; ++m) {
    const int rowb = mBase + wr * 64 + m * 16 + g * 4;
    #pragma unroll
    for (int n = 0; n < 4; ++n) {
      const int col = nBase + wc * 64 + n * 16 + ln;
      const float bv = bias[col];
      if (EPI == 0) {
        const int part = col >> 10;          // 0=q,1=k,2=v
        const int c = col & 1023;
        const int hh = c >> 6, d = c & 63;
        const int bb = rowb >> 10, s0 = rowb & 1023;
        const int bh = bb * NHEADS + hh;
        if (part == 2) {                     // V^T: 4 consecutive s -> 8B store
          ushort4 pv;
          pv.x = f2bf(acc[m][n][0] + bv); pv.y = f2bf(acc[m][n][1] + bv);
          pv.z = f2bf(acc[m][n][2] + bv); pv.w = f2bf(acc[m][n][3] + bv);
          *(ushort4*)&vb[(bh * DHEAD + d) * SLEN + s0] = pv;
        } else {
          unsigned short* dst = (part == 0) ? qb : kb;
          #pragma unroll
          for (int r = 0; r < 4; ++r)
            dst[(bh * SLEN + s0 + r) * DHEAD + d] = f2bf(acc[m][n][r] + bv);
        }
      } else {
        #pragma unroll
        for (int r = 0; r < 4; ++r)
          outf[(rowb + r) * N + col] = acc[m][n][r] + bv;
      }
    }
  }
}

// ---------------- flash attention: 2 fused q-chains/wave + KV-split x4 -------
// 256-thr blocks = 4 waves; block owns 64 q rows (chains A,B of 32); wave w
// does key-tiles t == w (mod 4). S^T = mfma(K,Q): lane q=lane&31, key
// crow(r,hi)=(r&3)+8*(r>>2)+4*hi. O^T = mfma(V^T,P): d=crow(r,hi) (+32 o1).
__global__ __launch_bounds__(256) void attn(
    const unsigned short* __restrict__ qb, const unsigned short* __restrict__ kb,
    const unsigned short* __restrict__ vb, const int* __restrict__ Lp,
    unsigned short* __restrict__ yb) {
  const int bid = blockIdx.x;
  const int lid = (bid & 7) * 128 + (bid >> 3);   // XCD-chunked swizzle (1024%8==0)
  const int bh = lid >> 4, qp = lid & 15;
  const int b = bh >> 4, h = bh & 15;
  const int L = Lp[b];
  const int tid = threadIdx.x;
  const int w = tid >> 6, l = tid & 63;
  const int l31 = l & 31, hi = l >> 5;
  const int q0 = qp * 64;
  const int qA = q0 + l31, qB = q0 + 32 + l31;
  const int qwA = 2 * qp, qwB = 2 * qp + 1;

  const unsigned short* qp_ = qb + (size_t)bh * SLEN * DHEAD;
  const unsigned short* kp  = kb + (size_t)bh * SLEN * DHEAD;
  const unsigned short* vp  = vb + (size_t)bh * DHEAD * SLEN;

  bf16x8 qfA[4], qfB[4];
  #pragma unroll
  for (int c = 0; c < 4; ++c) {
    qfA[c] = *(const bf16x8*)&qp_[qA * DHEAD + c * 16 + hi * 8];
    qfB[c] = *(const bf16x8*)&qp_[qB * DHEAD + c * 16 + hi * 8];
  }

  f32x16 o0A = {}, o1A = {}, o0B = {}, o1B = {};
  float mA = -__builtin_inff(), lsA = 0.f;
  float mB = -__builtin_inff(), lsB = 0.f;
  const float C = 0.18033688011112042f;          // 0.125 * log2(e)

  const bool noneA = q0 >= L,        noneB = (q0 + 32) >= L;
  const bool allA  = (q0 + 31) < L,  allB  = (q0 + 63) < L;
  const int tsA = (allA && L < SLEN) ? qwA : 0;
  const int tsB = (allB && L < SLEN) ? qwB : 0;
  const int ts  = tsA < tsB ? tsA : tsB;
  const int tlo = ts + ((w - ts) & 3);

  const int tp = tlo < 32 ? tlo : 31;
  bf16x8 kcur[4];
  #pragma unroll
  for (int c = 0; c < 4; ++c)
    kcur[c] = *(const bf16x8*)&kp[(tp * 32 + l31) * DHEAD + c * 16 + hi * 8];

#define SM_PV(SUF)                                                          \
  {                                                                         \
    const bool domask = (!none##SUF) && (t <= qw##SUF);                     \
    float pm;                                                               \
    if (domask) {                                                           \
      _Pragma("unroll")                                                     \
      for (int r = 0; r < 16; ++r) {                                        \
        const int key = kb0 + (r & 3) + 8 * (r >> 2) + 4 * hi;              \
        float s = e##SUF[r] * C;                                            \
        if ((q##SUF < L) && (key <= q##SUF)) s = -1e30f;                    \
        e##SUF[r] = s;                                                      \
      }                                                                     \
    } else {                                                                \
      _Pragma("unroll")                                                     \
      for (int r = 0; r < 16; ++r) e##SUF[r] *= C;                          \
    }                                                                       \
    {                                                                       \
      float t0 = fmaxf(e##SUF[0], e##SUF[1]),  t1 = fmaxf(e##SUF[2], e##SUF[3]);   \
      float t2 = fmaxf(e##SUF[4], e##SUF[5]),  t3 = fmaxf(e##SUF[6], e##SUF[7]);   \
      float t4 = fmaxf(e##SUF[8], e##SUF[9]),  t5 = fmaxf(e##SUF[10], e##SUF[11]); \
      float t6 = fmaxf(e##SUF[12], e##SUF[13]), t7 = fmaxf(e##SUF[14], e##SUF[15]);\
      t0 = fmaxf(t0, t1); t2 = fmaxf(t2, t3); t4 = fmaxf(t4, t5); t6 = fmaxf(t6, t7); \
      pm = fmaxf(fmaxf(t0, t2), fmaxf(t4, t6));                             \
    }                                                                       \
    pm = fmaxf(pm, __shfl_xor(pm, 32));                                     \
    const bool need = !__all(pm <= m##SUF + 8.0f);                          \
    if (need) {                                                             \
      const float mn = fmaxf(m##SUF, pm);                                   \
      const float a = exp2f(m##SUF - mn);                                   \
      _Pragma("unroll")                                                     \
      for (int r = 0; r < 16; ++r) { o0##SUF[r] *= a; o1##SUF[r] *= a; }    \
      ls##SUF *= a; m##SUF = mn;                                            \
    }                                                                       \
    float sum = 0.f;                                                        \
    _Pragma("unroll")                                                       \
    for (int r = 0; r < 16; ++r) {                                          \
      const float pe = exp2f(e##SUF[r] - m##SUF);                           \
      e##SUF[r] = pe; sum += pe;                                            \
    }                                                                       \
    sum += __shfl_xor(sum, 32);                                             \
    ls##SUF += sum;                                                         \
    bf16x8 pbf[2];                                                          \
    _Pragma("unroll")                                                       \
    for (int kc = 0; kc < 2; ++kc) {                                        \
      const unsigned wA_ = pack2(e##SUF[8*kc+0], e##SUF[8*kc+1]);           \
      const unsigned wB_ = pack2(e##SUF[8*kc+2], e##SUF[8*kc+3]);           \
      const unsigned wC_ = pack2(e##SUF[8*kc+4], e##SUF[8*kc+5]);           \
      const unsigned wD_ = pack2(e##SUF[8*kc+6], e##SUF[8*kc+7]);           \
      const unsigned pA_ = __shfl_xor(wA_, 32);                             \
      const unsigned pB_ = __shfl_xor(wB_, 32);                             \
      const unsigned pC_ = __shfl_xor(wC_, 32);                             \
      const unsigned pD_ = __shfl_xor(wD_, 32);                             \
      union { unsigned u[4]; bf16x8 v; } pk;                                \
      pk.u[0] = hi ? pC_ : wA_;                                             \
      pk.u[1] = hi ? pD_ : wB_;                                             \
      pk.u[2] = hi ? wC_ : pA_;                                             \
      pk.u[3] = hi ? wD_ : pB_;                                             \
      pbf[kc] = pk.v;                                                       \
    }                                                                       \
    __builtin_amdgcn_s_setprio(1);                                          \
    o0##SUF = MFMA32(vf0[0], pbf[0], o0##SUF);                              \
    o1##SUF = MFMA32(vf1[0], pbf[0], o1##SUF);                              \
    o0##SUF = MFMA32(vf0[1], pbf[1], o0##SUF);                              \
    o1##SUF = MFMA32(vf1[1], pbf[1], o1##SUF);                              \
    __builtin_amdgcn_s_setprio(0);                                          \
  }

  for (int t = tlo; t < 32; t += 4) {
    const int kb0 = t * 32;
    const int tn = (t + 4 < 32) ? (t + 4) : t;
    bf16x8 knxt[4];
    #pragma unroll
    for (int c = 0; c < 4; ++c)
      knxt[c] = *(const bf16x8*)&kp[(tn * 32 + l31) * DHEAD + c * 16 + hi * 8];
    bf16x8 vf0[2], vf1[2];
    #pragma unroll
    for (int kc = 0; kc < 2; ++kc) {
      vf0[kc] = *(const bf16x8*)&vp[l31 * SLEN + kb0 + kc * 16 + hi * 8];
      vf1[kc] = *(const bf16x8*)&vp[(32 + l31) * SLEN + kb0 + kc * 16 + hi * 8];
    }

    f32x16 eA = {}, eB = {};
    __builtin_amdgcn_s_setprio(1);
    #pragma unroll
    for (int c = 0; c < 4; ++c) eA = MFMA32(kcur[c], qfA[c], eA);
    #pragma unroll
    for (int c = 0; c < 4; ++c) eB = MFMA32(kcur[c], qfB[c], eB);
    __builtin_amdgcn_s_setprio(0);

    const bool doA = t >= tsA, doB = t >= tsB;
    if (doA && doB) {        // fused block: compiler interleaves both chains
      SM_PV(A)
      SM_PV(B)
    } else if (doA) {
      SM_PV(A)
    } else if (doB) {
      SM_PV(B)
    }

    #pragma unroll
    for (int c = 0; c < 4; ++c) kcur[c] = knxt[c];
  }
#undef SM_PV

  // ---------------- 4-wave pairwise-tree merge (both chains) ----------------
  __shared__ float mlsA[4][2][32], mlsB[4][2][32];
  __shared__ __align__(16) float obufA[2][32][65], obufB[2][32][65];
  if (hi == 0) {
    mlsA[w][0][l31] = mA; mlsA[w][1][l31] = lsA;
    mlsB[w][0][l31] = mB; mlsB[w][1][l31] = lsB;
  }
  __syncthreads();
  {
    const float a0 = mlsA[0][0][l31], a1 = mlsA[1][0][l31];
    const float a2 = mlsA[2][0][l31], a3 = mlsA[3][0][l31];
    const float msA = fmaxf(fmaxf(a0, a1), fmaxf(a2, a3));
    const float dnA = mlsA[0][1][l31] * exp2f(a0 - msA)
                    + mlsA[1][1][l31] * exp2f(a1 - msA)
                    + mlsA[2][1][l31] * exp2f(a2 - msA)
                    + mlsA[3][1][l31] * exp2f(a3 - msA);
    const float swA = exp2f(mA - msA) / dnA;
    #pragma unroll
    for (int r = 0; r < 16; ++r) { o0A[r] *= swA; o1A[r] *= swA; }
    const float b0 = mlsB[0][0][l31], b1 = mlsB[1][0][l31];
    const float b2 = mlsB[2][0][l31], b3 = mlsB[3][0][l31];
    const float msB = fmaxf(fmaxf(b0, b1), fmaxf(b2, b3));
    const float dnB = mlsB[0][1][l31] * exp2f(b0 - msB)
                    + mlsB[1][1][l31] * exp2f(b1 - msB)
                    + mlsB[2][1][l31] * exp2f(b2 - msB)
                    + mlsB[3][1][l31] * exp2f(b3 - msB);
    const float swB = exp2f(mB - msB) / dnB;
    #pragma unroll
    for (int r = 0; r < 16; ++r) { o0B[r] *= swB; o1B[r] *= swB; }
  }
  if (w >= 2) {
    #pragma unroll
    for (int r = 0; r < 16; ++r) {
      const int d = (r & 3) + 8 * (r >> 2) + 4 * hi;
      obufA[w - 2][l31][d]      = o0A[r];
      obufA[w - 2][l31][d + 32] = o1A[r];
      obufB[w - 2][l31][d]      = o0B[r];
      obufB[w - 2][l31][d + 32] = o1B[r];
    }
  }
  __syncthreads();
  if (w < 2) {
    #pragma unroll
    for (int r = 0; r < 16; ++r) {
      const int d = (r & 3) + 8 * (r >> 2) + 4 * hi;
      o0A[r] += obufA[w][l31][d];
      o1A[r] += obufA[w][l31][d + 32];
      o0B[r] += obufB[w][l31][d];
      o1B[r] += obufB[w][l31][d + 32];
    }
  }
  __syncthreads();
  if (w == 1) {
    #pragma unroll
    for (int r = 0; r < 16; ++r) {
      const int d = (r & 3) + 8 * (r >> 2) + 4 * hi;
      obufA[0][l31][d]      = o0A[r];
      obufA[0][l31][d + 32] = o1A[r];
      obufB[0][l31][d]      = o0B[r];
      obufB[0][l31][d + 32] = o1B[r];
    }
  }
  __syncthreads();
  if (w == 0) {
    #pragma unroll
    for (int r = 0; r < 16; ++r) {
      const int d = (r & 3) + 8 * (r >> 2) + 4 * hi;
      o0A[r] += obufA[0][l31][d];
      o1A[r] += obufA[0][l31][d + 32];
      o0B[r] += obufB[0][l31][d];
      o1B[r] += obufB[0][l31][d + 32];
    }
    unsigned short* yrA = yb + (size_t)(b * SLEN + qA) * EDIM + h * DHEAD;
    unsigned short* yrB = yb + (size_t)(b * SLEN + qB) * EDIM + h * DHEAD;
    #pragma unroll
    for (int rq = 0; rq < 4; ++rq) {
      ushort4 s0, s1;
      s0.x = f2bf(o0A[4*rq+0]); s0.y = f2bf(o0A[4*rq+1]);
      s0.z = f2bf(o0A[4*rq+2]); s0.w = f2bf(o0A[4*rq+3]);
      s1.x = f2bf(o1A[4*rq+0]); s1.y = f2bf(o1A[4*rq+1]);
      s1.z = f2bf(o1A[4*rq+2]); s1.w = f2bf(o1A[4*rq+3]);
      *(ushort4*)&yrA[8*rq + 4*hi]      = s0;
      *(ushort4*)&yrA[32 + 8*rq + 4*hi] = s1;
      s0.x = f2bf(o0B[4*rq+0]); s0.y = f2bf(o0B[4*rq+1]);
      s0.z = f2bf(o0B[4*rq+2]); s0.w = f2bf(o0B[4*rq+3]);
      s1.x = f2bf(o1B[4*rq+0]); s1.y = f2bf(o1B[4*rq+1]);
      s1.z = f2bf(o1B[4*rq+2]); s1.w = f2bf(o1B[4*rq+3]);
      *(ushort4*)&yrB[8*rq + 4*hi]      = s0;
      *(ushort4*)&yrB[32 + 8*rq + 4*hi] = s1;
    }
  }
}

// ---------------- launch ----------------
extern "C" void kernel_launch(void* const* d_in, const int* in_sizes, int n_in,
                              void* d_out, int out_size, void* d_ws, size_t ws_size,
                              hipStream_t stream) {
  const float* x    = (const float*)d_in[0];
  const int*   mask = (const int*)d_in[1];
  const float* wqkv = (const float*)d_in[2];
  const float* bqkv = (const float*)d_in[3];
  const float* wout = (const float*)d_in[4];
  const float* bout = (const float*)d_in[5];
  float* out = (float*)d_out;

  char* ws = (char*)d_ws;
  const size_t SZ_X   = (size_t)BATCH * SLEN * EDIM * 2;   // 8MB
  const size_t SZ_WQ  = (size_t)3 * EDIM * EDIM * 2;       // 6MB
  const size_t SZ_WO  = (size_t)EDIM * EDIM * 2;       // 2MB
  const size_t SZ_QKV = (size_t)BATCH * NHEADS * SLEN * DHEAD * 2;  // 8MB each

  unsigned short* xb   = (unsigned short*)ws;               ws += SZ_X;
  unsigned short* wqb  = (unsigned short*)ws;               ws += SZ_WQ;
  unsigned short* wob  = (unsigned short*)ws;               ws += SZ_WO;
  unsigned short* qbuf = (unsigned short*)ws;               ws += SZ_QKV;
  unsigned short* kbuf = (unsigned short*)ws;               ws += SZ_QKV;
  unsigned short* vbuf = (unsigned short*)ws;               ws += SZ_QKV;
  unsigned short* ybuf = (unsigned short*)ws;               ws += SZ_X;
  int* Lbuf = (int*)ws;

  prep_cast<<<8192, 256, 0, stream>>>(x, wqkv, wout, xb, wqb, wob);
  mask_sum<<<BATCH, 256, 0, stream>>>(mask, Lbuf);
  gemm_bt<0><<<(4096 / 128) * (3072 / 128), 256, 0, stream>>>(
      xb, wqb, 4096, 3072, 1024, bqkv, nullptr, qbuf, kbuf, vbuf);
  attn<<<BATCH * NHEADS * (SLEN / 64), 256, 0, stream>>>(qbuf, kbuf, vbuf, Lbuf, ybuf);
  gemm_bt<1><<<(4096 / 128) * (1024 / 128), 256, 0, stream>>>(
      ybuf, wob, 4096, 1024, 1024, bout, out, nullptr, nullptr, nullptr);
}

// Round 11
// 213.954 us; speedup vs baseline: 1.1076x; 1.0416x over previous
//
#include <hip/hip_runtime.h>

// Fused MHA: x(4,1024,1024) fp32, mask(4,1024) i32, w_qkv(3072,1024), b_qkv,
// w_out(1024,1024), b_out -> out(4,1024,1024) fp32.
// R10 (resubmit; broker timeout): V-permuted storage => zero-exchange P-pack
//      (removes 4 shfl/chain/tile); deferred cross-half l-sum (removes 1).
//      Only pm max shfl remains per tile. GEMMs unchanged from R9 except V^T
//      position bits.

#define NHEADS 16
#define DHEAD  64
#define EDIM   1024
#define SLEN   1024
#define BATCH  4

typedef short bf16x8 __attribute__((ext_vector_type(8)));
typedef float f32x4  __attribute__((ext_vector_type(4)));
typedef float f32x16 __attribute__((ext_vector_type(16)));

#define MFMA_BF16(a,b,c) __builtin_amdgcn_mfma_f32_16x16x32_bf16((a),(b),(c),0,0,0)
#define MFMA32(a,b,c)    __builtin_amdgcn_mfma_f32_32x32x16_bf16((a),(b),(c),0,0,0)

typedef const __attribute__((address_space(1))) void gvoid_t;
typedef __attribute__((address_space(3))) void lvoid_t;

__device__ __forceinline__ unsigned short f2bf(float x) {
  union { float f; unsigned int u; } v; v.f = x;
  unsigned int r = v.u + 0x7fffu + ((v.u >> 16) & 1u);
  return (unsigned short)(r >> 16);
}

__device__ __forceinline__ unsigned pack2(float lo, float hi) {
  return (unsigned)f2bf(lo) | ((unsigned)f2bf(hi) << 16);
}

__device__ __forceinline__ void gl2lds16(const void* g, void* l) {
  __builtin_amdgcn_global_load_lds((gvoid_t*)g, (lvoid_t*)l, 16, 0, 0);
}

// ---------------- prep: fp32 -> bf16 casts ----------------
__global__ __launch_bounds__(256) void prep_cast(
    const float* __restrict__ x, const float* __restrict__ wq,
    const float* __restrict__ wo,
    unsigned short* __restrict__ xb, unsigned short* __restrict__ wqb,
    unsigned short* __restrict__ wob) {
  int i = blockIdx.x * 256 + threadIdx.x;
  const int NX  = BATCH * SLEN * EDIM / 4;   // 1048576
  const int NW1 = 3 * EDIM * EDIM / 4;       // 786432
  const float4* src; unsigned short* dst; int j;
  if (i < NX)           { src = (const float4*)x;  dst = xb;  j = i; }
  else if (i < NX+NW1)  { src = (const float4*)wq; dst = wqb; j = i - NX; }
  else                  { src = (const float4*)wo; dst = wob; j = i - NX - NW1; }
  float4 v = src[j];
  ushort4 o;
  o.x = f2bf(v.x); o.y = f2bf(v.y); o.z = f2bf(v.z); o.w = f2bf(v.w);
  ((ushort4*)dst)[j] = o;
}

// ---------------- mask row-sum: L[b] ----------------
__global__ __launch_bounds__(256) void mask_sum(const int* __restrict__ mask,
                                                int* __restrict__ L) {
  int b = blockIdx.x;
  int t = threadIdx.x;
  int s = 0;
  for (int i = t; i < SLEN; i += 256) s += mask[b * SLEN + i];
  #pragma unroll
  for (int m = 1; m < 64; m <<= 1) s += __shfl_xor(s, m);
  __shared__ int part[4];
  if ((t & 63) == 0) part[t >> 6] = s;
  __syncthreads();
  if (t == 0) L[b] = part[0] + part[1] + part[2] + part[3];
}

// ---------------- GEMM C = A @ B^T, 2-phase double-buffered ----------------
template<int EPI>
__global__ __launch_bounds__(256) void gemm_bt(
    const unsigned short* __restrict__ A, const unsigned short* __restrict__ B,
    int M, int N, int K,
    const float* __restrict__ bias,
    float* __restrict__ outf,
    unsigned short* __restrict__ qb, unsigned short* __restrict__ kb,
    unsigned short* __restrict__ vb) {
  __shared__ __align__(16) unsigned short lds_a[2][128 * 32];
  __shared__ __align__(16) unsigned short lds_b[2][128 * 32];
  const int tid = threadIdx.x;
  const int w = tid >> 6, l = tid & 63;
  const int g = l >> 4, ln = l & 15;
  const int ntile = N >> 7;
  // XCD-chunked swizzle (grid % 8 == 0 for both instantiations)
  const int nwg = gridDim.x;
  const int bid = blockIdx.x;
  const int wg = (bid & 7) * (nwg >> 3) + (bid >> 3);
  const int tm = wg / ntile, tn = wg % ntile;
  const int mBase = tm << 7, nBase = tn << 7;
  const int wr = w >> 1, wc = w & 1;

  f32x4 zz = {0.f, 0.f, 0.f, 0.f};
  f32x4 acc[4][4];
  #pragma unroll
  for (int m = 0; m < 4; ++m)
    #pragma unroll
    for (int n = 0; n < 4; ++n) acc[m][n] = zz;

  const int u0 = tid, u1 = tid + 256;
  const int r0 = u0 >> 2, c0 = (u0 & 3) << 3;
  const int r1 = u1 >> 2, c1 = (u1 & 3) << 3;
  const unsigned short* Ab = A + mBase * K;
  const unsigned short* Bb = B + nBase * K;
  const int d0 = (w * 64) * 8, d1 = (256 + w * 64) * 8;

  const int NT = K >> 5;
  // prologue: stage tile 0 into buf 0
  gl2lds16(Ab + r0 * K + c0, &lds_a[0][d0]);
  gl2lds16(Ab + r1 * K + c1, &lds_a[0][d1]);
  gl2lds16(Bb + r0 * K + c0, &lds_b[0][d0]);
  gl2lds16(Bb + r1 * K + c1, &lds_b[0][d1]);
  __syncthreads();

  int cur = 0;
  for (int t = 0; t < NT; ++t) {
    if (t + 1 < NT) {   // stage next tile first (latency hides under MFMA)
      const int kn = (t + 1) << 5;
      gl2lds16(Ab + r0 * K + kn + c0, &lds_a[cur ^ 1][d0]);
      gl2lds16(Ab + r1 * K + kn + c1, &lds_a[cur ^ 1][d1]);
      gl2lds16(Bb + r0 * K + kn + c0, &lds_b[cur ^ 1][d0]);
      gl2lds16(Bb + r1 * K + kn + c1, &lds_b[cur ^ 1][d1]);
    }
    bf16x8 af[4], bfr[4];
    #pragma unroll
    for (int m = 0; m < 4; ++m)
      af[m] = *(const bf16x8*)&lds_a[cur][(wr * 64 + m * 16 + ln) * 32 + g * 8];
    #pragma unroll
    for (int n = 0; n < 4; ++n)
      bfr[n] = *(const bf16x8*)&lds_b[cur][(wc * 64 + n * 16 + ln) * 32 + g * 8];
    __builtin_amdgcn_s_setprio(1);
    #pragma unroll
    for (int m = 0; m < 4; ++m)
      #pragma unroll
      for (int n = 0; n < 4; ++n)
        acc[m][n] = MFMA_BF16(af[m], bfr[n], acc[m][n]);
    __builtin_amdgcn_s_setprio(0);
    __syncthreads();   // drains vmcnt(0)+lgkmcnt(0): next buffer staged & ready
    cur ^= 1;
  }

  #pragma unroll
  for (int m = 0; m < 4; ++m) {
    const int rowb = mBase + wr * 64 + m * 16 + g * 4;
    #pragma unroll
    for (int n = 0; n < 4; ++n) {
      const int col = nBase + wc * 64 + n * 16 + ln;
      const float bv = bias[col];
      if (EPI == 0) {
        const int part = col >> 10;          // 0=q,1=k,2=v
        const int c = col & 1023;
        const int hh = c >> 6, d = c & 63;
        const int bb = rowb >> 10, s0 = rowb & 1023;
        const int bh = bb * NHEADS + hh;
        if (part == 2) {
          // V^T with key permutation baked in: key k -> position
          // p(k) = (k&~15) | 8*((k>>2)&1) | 4*((k>>3)&1) | (k&3).
          // s0 % 4 == 0, so 4 consecutive keys stay one contiguous store.
          const int sp = (s0 & ~15) | (((s0 >> 2) & 1) << 3) | (((s0 >> 3) & 1) << 2);
          ushort4 pv;
          pv.x = f2bf(acc[m][n][0] + bv); pv.y = f2bf(acc[m][n][1] + bv);
          pv.z = f2bf(acc[m][n][2] + bv); pv.w = f2bf(acc[m][n][3] + bv);
          *(ushort4*)&vb[(bh * DHEAD + d) * SLEN + sp] = pv;
        } else {
          unsigned short* dst = (part == 0) ? qb : kb;
          #pragma unroll
          for (int r = 0; r < 4; ++r)
            dst[(bh * SLEN + s0 + r) * DHEAD + d] = f2bf(acc[m][n][r] + bv);
        }
      } else {
        #pragma unroll
        for (int r = 0; r < 4; ++r)
          outf[(rowb + r) * N + col] = acc[m][n][r] + bv;
      }
    }
  }
}

// ---------------- flash attention: 2 fused q-chains/wave + KV-split x4 -------
// 256-thr blocks = 4 waves; block owns 64 q rows (chains A,B of 32); wave w
// does key-tiles t == w (mod 4). S^T = mfma(K,Q): lane q=lane&31, key
// crow(r,hi)=(r&3)+8*(r>>2)+4*hi. O^T = mfma(V'^T,P'): V stored key-permuted
// so P-pack is pure lane-local (no cross-lane exchange).
__global__ __launch_bounds__(256) void attn(
    const unsigned short* __restrict__ qb, const unsigned short* __restrict__ kb,
    const unsigned short* __restrict__ vb, const int* __restrict__ Lp,
    unsigned short* __restrict__ yb) {
  const int bid = blockIdx.x;
  const int lid = (bid & 7) * 128 + (bid >> 3);   // XCD-chunked swizzle (1024%8==0)
  const int bh = lid >> 4, qp = lid & 15;
  const int b = bh >> 4, h = bh & 15;
  const int L = Lp[b];
  const int tid = threadIdx.x;
  const int w = tid >> 6, l = tid & 63;
  const int l31 = l & 31, hi = l >> 5;
  const int q0 = qp * 64;
  const int qA = q0 + l31, qB = q0 + 32 + l31;
  const int qwA = 2 * qp, qwB = 2 * qp + 1;

  const unsigned short* qp_ = qb + (size_t)bh * SLEN * DHEAD;
  const unsigned short* kp  = kb + (size_t)bh * SLEN * DHEAD;
  const unsigned short* vp  = vb + (size_t)bh * DHEAD * SLEN;

  bf16x8 qfA[4], qfB[4];
  #pragma unroll
  for (int c = 0; c < 4; ++c) {
    qfA[c] = *(const bf16x8*)&qp_[qA * DHEAD + c * 16 + hi * 8];
    qfB[c] = *(const bf16x8*)&qp_[qB * DHEAD + c * 16 + hi * 8];
  }

  f32x16 o0A = {}, o1A = {}, o0B = {}, o1B = {};
  float mA = -__builtin_inff(), lsA = 0.f;   // ls = per-half partial sum
  float mB = -__builtin_inff(), lsB = 0.f;
  const float C = 0.18033688011112042f;      // 0.125 * log2(e)

  const bool noneA = q0 >= L,        noneB = (q0 + 32) >= L;
  const bool allA  = (q0 + 31) < L,  allB  = (q0 + 63) < L;
  const int tsA = (allA && L < SLEN) ? qwA : 0;
  const int tsB = (allB && L < SLEN) ? qwB : 0;
  const int ts  = tsA < tsB ? tsA : tsB;
  const int tlo = ts + ((w - ts) & 3);

  const int tp = tlo < 32 ? tlo : 31;
  bf16x8 kcur[4];
  #pragma unroll
  for (int c = 0; c < 4; ++c)
    kcur[c] = *(const bf16x8*)&kp[(tp * 32 + l31) * DHEAD + c * 16 + hi * 8];

#define SM_PV(SUF)                                                          \
  {                                                                         \
    const bool domask = (!none##SUF) && (t <= qw##SUF);                     \
    float pm;                                                               \
    if (domask) {                                                           \
      _Pragma("unroll")                                                     \
      for (int r = 0; r < 16; ++r) {                                        \
        const int key = kb0 + (r & 3) + 8 * (r >> 2) + 4 * hi;              \
        float s = e##SUF[r] * C;                                            \
        if ((q##SUF < L) && (key <= q##SUF)) s = -1e30f;                    \
        e##SUF[r] = s;                                                      \
      }                                                                     \
    } else {                                                                \
      _Pragma("unroll")                                                     \
      for (int r = 0; r < 16; ++r) e##SUF[r] *= C;                          \
    }                                                                       \
    {                                                                       \
      float t0 = fmaxf(e##SUF[0], e##SUF[1]),  t1 = fmaxf(e##SUF[2], e##SUF[3]);   \
      float t2 = fmaxf(e##SUF[4], e##SUF[5]),  t3 = fmaxf(e##SUF[6], e##SUF[7]);   \
      float t4 = fmaxf(e##SUF[8], e##SUF[9]),  t5 = fmaxf(e##SUF[10], e##SUF[11]); \
      float t6 = fmaxf(e##SUF[12], e##SUF[13]), t7 = fmaxf(e##SUF[14], e##SUF[15]);\
      t0 = fmaxf(t0, t1); t2 = fmaxf(t2, t3); t4 = fmaxf(t4, t5); t6 = fmaxf(t6, t7); \
      pm = fmaxf(fmaxf(t0, t2), fmaxf(t4, t6));                             \
    }                                                                       \
    pm = fmaxf(pm, __shfl_xor(pm, 32));                                     \
    const bool need = !__all(pm <= m##SUF + 8.0f);                          \
    if (need) {                                                             \
      const float mn = fmaxf(m##SUF, pm);                                   \
      const float a = exp2f(m##SUF - mn);                                   \
      _Pragma("unroll")                                                     \
      for (int r = 0; r < 16; ++r) { o0##SUF[r] *= a; o1##SUF[r] *= a; }    \
      ls##SUF *= a; m##SUF = mn;                                            \
    }                                                                       \
    float sum = 0.f;                                                        \
    _Pragma("unroll")                                                       \
    for (int r = 0; r < 16; ++r) {                                          \
      const float pe = exp2f(e##SUF[r] - m##SUF);                           \
      e##SUF[r] = pe; sum += pe;                                            \
    }                                                                       \
    ls##SUF += sum;   /* per-half partial; cross-half deferred to merge */  \
    bf16x8 pbf[2];                                                          \
    _Pragma("unroll")                                                       \
    for (int kc = 0; kc < 2; ++kc) {                                        \
      union { unsigned u[4]; bf16x8 v; } pk;                                \
      pk.u[0] = pack2(e##SUF[8*kc+0], e##SUF[8*kc+1]);                      \
      pk.u[1] = pack2(e##SUF[8*kc+2], e##SUF[8*kc+3]);                      \
      pk.u[2] = pack2(e##SUF[8*kc+4], e##SUF[8*kc+5]);                      \
      pk.u[3] = pack2(e##SUF[8*kc+6], e##SUF[8*kc+7]);                      \
      pbf[kc] = pk.v;                                                       \
    }                                                                       \
    __builtin_amdgcn_s_setprio(1);                                          \
    o0##SUF = MFMA32(vf0[0], pbf[0], o0##SUF);                              \
    o1##SUF = MFMA32(vf1[0], pbf[0], o1##SUF);                              \
    o0##SUF = MFMA32(vf0[1], pbf[1], o0##SUF);                              \
    o1##SUF = MFMA32(vf1[1], pbf[1], o1##SUF);                              \
    __builtin_amdgcn_s_setprio(0);                                          \
  }

  for (int t = tlo; t < 32; t += 4) {
    const int kb0 = t * 32;
    const int tn = (t + 4 < 32) ? (t + 4) : t;
    bf16x8 knxt[4];
    #pragma unroll
    for (int c = 0; c < 4; ++c)
      knxt[c] = *(const bf16x8*)&kp[(tn * 32 + l31) * DHEAD + c * 16 + hi * 8];
    bf16x8 vf0[2], vf1[2];
    #pragma unroll
    for (int kc = 0; kc < 2; ++kc) {
      vf0[kc] = *(const bf16x8*)&vp[l31 * SLEN + kb0 + kc * 16 + hi * 8];
      vf1[kc] = *(const bf16x8*)&vp[(32 + l31) * SLEN + kb0 + kc * 16 + hi * 8];
    }

    f32x16 eA = {}, eB = {};
    __builtin_amdgcn_s_setprio(1);
    #pragma unroll
    for (int c = 0; c < 4; ++c) eA = MFMA32(kcur[c], qfA[c], eA);
    #pragma unroll
    for (int c = 0; c < 4; ++c) eB = MFMA32(kcur[c], qfB[c], eB);
    __builtin_amdgcn_s_setprio(0);

    const bool doA = t >= tsA, doB = t >= tsB;
    if (doA && doB) {        // fused block: compiler interleaves both chains
      SM_PV(A)
      SM_PV(B)
    } else if (doA) {
      SM_PV(A)
    } else if (doB) {
      SM_PV(B)
    }

    #pragma unroll
    for (int c = 0; c < 4; ++c) kcur[c] = knxt[c];
  }
#undef SM_PV

  // cross-half l-sum, once per kernel
  const float lwA = lsA + __shfl_xor(lsA, 32);
  const float lwB = lsB + __shfl_xor(lsB, 32);

  // ---------------- 4-wave pairwise-tree merge (both chains) ----------------
  __shared__ float mlsA[4][2][32], mlsB[4][2][32];
  __shared__ __align__(16) float obufA[2][32][65], obufB[2][32][65];
  if (hi == 0) {
    mlsA[w][0][l31] = mA; mlsA[w][1][l31] = lwA;
    mlsB[w][0][l31] = mB; mlsB[w][1][l31] = lwB;
  }
  __syncthreads();
  {
    const float a0 = mlsA[0][0][l31], a1 = mlsA[1][0][l31];
    const float a2 = mlsA[2][0][l31], a3 = mlsA[3][0][l31];
    const float msA = fmaxf(fmaxf(a0, a1), fmaxf(a2, a3));
    const float dnA = mlsA[0][1][l31] * exp2f(a0 - msA)
                    + mlsA[1][1][l31] * exp2f(a1 - msA)
                    + mlsA[2][1][l31] * exp2f(a2 - msA)
                    + mlsA[3][1][l31] * exp2f(a3 - msA);
    const float swA = exp2f(mA - msA) / dnA;
    #pragma unroll
    for (int r = 0; r < 16; ++r) { o0A[r] *= swA; o1A[r] *= swA; }
    const float b0 = mlsB[0][0][l31], b1 = mlsB[1][0][l31];
    const float b2 = mlsB[2][0][l31], b3 = mlsB[3][0][l31];
    const float msB = fmaxf(fmaxf(b0, b1), fmaxf(b2, b3));
    const float dnB = mlsB[0][1][l31] * exp2f(b0 - msB)
                    + mlsB[1][1][l31] * exp2f(b1 - msB)
                    + mlsB[2][1][l31] * exp2f(b2 - msB)
                    + mlsB[3][1][l31] * exp2f(b3 - msB);
    const float swB = exp2f(mB - msB) / dnB;
    #pragma unroll
    for (int r = 0; r < 16; ++r) { o0B[r] *= swB; o1B[r] *= swB; }
  }
  if (w >= 2) {
    #pragma unroll
    for (int r = 0; r < 16; ++r) {
      const int d = (r & 3) + 8 * (r >> 2) + 4 * hi;
      obufA[w - 2][l31][d]      = o0A[r];
      obufA[w - 2][l31][d + 32] = o1A[r];
      obufB[w - 2][l31][d]      = o0B[r];
      obufB[w - 2][l31][d + 32] = o1B[r];
    }
  }
  __syncthreads();
  if (w < 2) {
    #pragma unroll
    for (int r = 0; r < 16; ++r) {
      const int d = (r & 3) + 8 * (r >> 2) + 4 * hi;
      o0A[r] += obufA[w][l31][d];
      o1A[r] += obufA[w][l31][d + 32];
      o0B[r] += obufB[w][l31][d];
      o1B[r] += obufB[w][l31][d + 32];
    }
  }
  __syncthreads();
  if (w == 1) {
    #pragma unroll
    for (int r = 0; r < 16; ++r) {
      const int d = (r & 3) + 8 * (r >> 2) + 4 * hi;
      obufA[0][l31][d]      = o0A[r];
      obufA[0][l31][d + 32] = o1A[r];
      obufB[0][l31][d]      = o0B[r];
      obufB[0][l31][d + 32] = o1B[r];
    }
  }
  __syncthreads();
  if (w == 0) {
    #pragma unroll
    for (int r = 0; r < 16; ++r) {
      const int d = (r & 3) + 8 * (r >> 2) + 4 * hi;
      o0A[r] += obufA[0][l31][d];
      o1A[r] += obufA[0][l31][d + 32];
      o0B[r] += obufB[0][l31][d];
      o1B[r] += obufB[0][l31][d + 32];
    }
    unsigned short* yrA = yb + (size_t)(b * SLEN + qA) * EDIM + h * DHEAD;
    unsigned short* yrB = yb + (size_t)(b * SLEN + qB) * EDIM + h * DHEAD;
    #pragma unroll
    for (int rq = 0; rq < 4; ++rq) {
      ushort4 s0, s1;
      s0.x = f2bf(o0A[4*rq+0]); s0.y = f2bf(o0A[4*rq+1]);
      s0.z = f2bf(o0A[4*rq+2]); s0.w = f2bf(o0A[4*rq+3]);
      s1.x = f2bf(o1A[4*rq+0]); s1.y = f2bf(o1A[4*rq+1]);
      s1.z = f2bf(o1A[4*rq+2]); s1.w = f2bf(o1A[4*rq+3]);
      *(ushort4*)&yrA[8*rq + 4*hi]      = s0;
      *(ushort4*)&yrA[32 + 8*rq + 4*hi] = s1;
      s0.x = f2bf(o0B[4*rq+0]); s0.y = f2bf(o0B[4*rq+1]);
      s0.z = f2bf(o0B[4*rq+2]); s0.w = f2bf(o0B[4*rq+3]);
      s1.x = f2bf(o1B[4*rq+0]); s1.y = f2bf(o1B[4*rq+1]);
      s1.z = f2bf(o1B[4*rq+2]); s1.w = f2bf(o1B[4*rq+3]);
      *(ushort4*)&yrB[8*rq + 4*hi]      = s0;
      *(ushort4*)&yrB[32 + 8*rq + 4*hi] = s1;
    }
  }
}

// ---------------- launch ----------------
extern "C" void kernel_launch(void* const* d_in, const int* in_sizes, int n_in,
                              void* d_out, int out_size, void* d_ws, size_t ws_size,
                              hipStream_t stream) {
  const float* x    = (const float*)d_in[0];
  const int*   mask = (const int*)d_in[1];
  const float* wqkv = (const float*)d_in[2];
  const float* bqkv = (const float*)d_in[3];
  const float* wout = (const float*)d_in[4];
  const float* bout = (const float*)d_in[5];
  float* out = (float*)d_out;

  char* ws = (char*)d_ws;
  const size_t SZ_X   = (size_t)BATCH * SLEN * EDIM * 2;   // 8MB
  const size_t SZ_WQ  = (size_t)3 * EDIM * EDIM * 2;       // 6MB
  const size_t SZ_WO  = (size_t)EDIM * EDIM * 2;           // 2MB
  const size_t SZ_QKV = (size_t)BATCH * NHEADS * SLEN * DHEAD * 2;  // 8MB each

  unsigned short* xb   = (unsigned short*)ws;               ws += SZ_X;
  unsigned short* wqb  = (unsigned short*)ws;               ws += SZ_WQ;
  unsigned short* wob  = (unsigned short*)ws;               ws += SZ_WO;
  unsigned short* qbuf = (unsigned short*)ws;               ws += SZ_QKV;
  unsigned short* kbuf = (unsigned short*)ws;               ws += SZ_QKV;
  unsigned short* vbuf = (unsigned short*)ws;               ws += SZ_QKV;
  unsigned short* ybuf = (unsigned short*)ws;               ws += SZ_X;
  int* Lbuf = (int*)ws;

  prep_cast<<<8192, 256, 0, stream>>>(x, wqkv, wout, xb, wqb, wob);
  mask_sum<<<BATCH, 256, 0, stream>>>(mask, Lbuf);
  gemm_bt<0><<<(4096 / 128) * (3072 / 128), 256, 0, stream>>>(
      xb, wqb, 4096, 3072, 1024, bqkv, nullptr, qbuf, kbuf, vbuf);
  attn<<<BATCH * NHEADS * (SLEN / 64), 256, 0, stream>>>(qbuf, kbuf, vbuf, Lbuf, ybuf);
  gemm_bt<1><<<(4096 / 128) * (1024 / 128), 256, 0, stream>>>(
      ybuf, wob, 4096, 1024, 1024, bout, out, nullptr, nullptr, nullptr);
}